// Round 1
// baseline (302.395 us; speedup 1.0000x reference)
//
#include <hip/hip_runtime.h>
#include <hip/hip_bf16.h>
#include <stdint.h>

// Problem constants
#define BB 16
#define NPTS 100000
#define NBOX 64
#define KTOP 2048
#define THRF 0.2f            // (float)(8*0.01*2.5)
#define C_LO 0.0399999f      // band around 0.2f^2 for exact-path fallback
#define C_HI 0.0400001f

// Workspace layout (in uint32 words)
#define HIST0_OFF 0                    // BB*256
#define CNT_OFF   (BB*256)             // BB
#define STATE_OFF (BB*256 + 16)       // BB*4 (16B aligned: 4112*4=16448)
#define LIST_OFF  (BB*256 + 16 + BB*4) // 4176 -> byte 16704 (16B aligned)
#define LIST_CAP  16384                // per-batch compacted capacity
#define MEMSET_BYTES (LIST_OFF * 4)

__device__ __forceinline__ uint32_t fmap(float f) {
    uint32_t b = __float_as_uint(f);
    return (b & 0x80000000u) ? ~b : (b | 0x80000000u);
}

// ---------- Pass 0: 256-bin MSB histogram per batch ----------
__global__ __launch_bounds__(256) void hist0_k(const float* __restrict__ scores,
                                               uint32_t* __restrict__ ws) {
    __shared__ uint32_t h[256];
    const int b = blockIdx.y;
    h[threadIdx.x] = 0;
    __syncthreads();
    const int p0 = blockIdx.x * 1024 + threadIdx.x * 4;
    if (p0 < NPTS) {
        const float4 v = *reinterpret_cast<const float4*>(scores + (size_t)b * NPTS + p0);
        atomicAdd(&h[fmap(v.x) >> 24], 1u);
        atomicAdd(&h[fmap(v.y) >> 24], 1u);
        atomicAdd(&h[fmap(v.z) >> 24], 1u);
        atomicAdd(&h[fmap(v.w) >> 24], 1u);
    }
    __syncthreads();
    uint32_t c = h[threadIdx.x];
    if (c) atomicAdd(&ws[HIST0_OFF + b * 256 + threadIdx.x], c);
}

// ---------- Scan pass-0 histogram: pick MSB bin ----------
__global__ void scan0_k(uint32_t* __restrict__ ws) {
    if (threadIdx.x != 0) return;
    const int b = blockIdx.x;
    const uint32_t* h = ws + HIST0_OFF + b * 256;
    uint32_t cum = 0;
    int bin = 255;
    for (; bin >= 0; --bin) {
        uint32_t c = h[bin];
        if (cum + c >= KTOP) break;
        cum += c;
    }
    uint32_t* st = ws + STATE_OFF + b * 4;
    st[0] = (uint32_t)bin << 24;  // prefix
    st[1] = KTOP - cum;           // krem
}

// ---------- Compact elements matching MSB prefix ----------
__global__ __launch_bounds__(256) void compact_k(const float* __restrict__ scores,
                                                 uint32_t* __restrict__ ws) {
    const int b = blockIdx.y;
    const uint32_t pref = ws[STATE_OFF + b * 4] >> 24;  // uniform
    const int p0 = blockIdx.x * 1024 + threadIdx.x * 4;
    if (p0 >= NPTS) return;
    const float4 v = *reinterpret_cast<const float4*>(scores + (size_t)b * NPTS + p0);
    uint32_t u[4] = {fmap(v.x), fmap(v.y), fmap(v.z), fmap(v.w)};
    uint32_t* list = ws + LIST_OFF + (size_t)b * LIST_CAP;
#pragma unroll
    for (int j = 0; j < 4; ++j) {
        if ((u[j] >> 24) == pref) {
            uint32_t pos = atomicAdd(&ws[CNT_OFF + b], 1u);
            if (pos < LIST_CAP) list[pos] = u[j];
        }
    }
}

// ---------- Finish radix select (3 passes in LDS) ----------
__global__ __launch_bounds__(1024) void finish_k(uint32_t* __restrict__ ws) {
    const int b = blockIdx.x;
    __shared__ uint32_t h[256];
    __shared__ uint32_t sPrefix, sKrem, sE;
    uint32_t* st = ws + STATE_OFF + b * 4;
    if (threadIdx.x == 0) {
        sPrefix = st[0];
        sKrem = st[1];
        sE = 0;
    }
    __syncthreads();
    uint32_t cnt = ws[CNT_OFF + b];
    if (cnt > LIST_CAP) cnt = LIST_CAP;
    const uint32_t* list = ws + LIST_OFF + (size_t)b * LIST_CAP;

#pragma unroll 1
    for (int shift = 16; shift >= 0; shift -= 8) {
        for (int i = threadIdx.x; i < 256; i += 1024) h[i] = 0;
        __syncthreads();
        const uint32_t pref = sPrefix;
        for (uint32_t i = threadIdx.x; i < cnt; i += 1024) {
            uint32_t u = list[i];
            if ((u >> (shift + 8)) == (pref >> (shift + 8)))
                atomicAdd(&h[(u >> shift) & 255u], 1u);
        }
        __syncthreads();
        if (threadIdx.x == 0) {
            uint32_t cum = 0;
            int bin = 255;
            for (; bin >= 0; --bin) {
                uint32_t c = h[bin];
                if (cum + c >= sKrem) break;
                cum += c;
            }
            sPrefix |= (uint32_t)bin << shift;
            sKrem -= cum;
            if (shift == 0) sE = h[bin];
        }
        __syncthreads();
    }
    if (threadIdx.x == 0) {
        uint32_t u = sPrefix;
        uint32_t bits = (u & 0x80000000u) ? (u & 0x7fffffffu) : ~u;
        st[0] = bits;        // T as float bits
        st[1] = sKrem;       // R: # of equals to take
        st[2] = sE;          // E: # of equals present
        st[3] = KTOP - sKrem;
    }
}

// ---------- exact (numpy-bit-identical) gt check for one point ----------
__device__ __noinline__ bool exact_gt(float px, float py, float pz,
                                      const float* __restrict__ C) {
    bool hit = false;
#pragma unroll 1
    for (int k = 0; k < NBOX; ++k) {
        float dx = px - C[3 * k + 0];
        float dy = py - C[3 * k + 1];
        float dz = pz - C[3 * k + 2];
        float d2 = __fadd_rn(__fadd_rn(__fmul_rn(dx, dx), __fmul_rn(dy, dy)),
                             __fmul_rn(dz, dz));
        if (__fsqrt_rn(d2) < THRF) hit = true;
    }
    return hit;
}

// ---------- Main: gt mask + prune mask + losses ----------
__global__ __launch_bounds__(256) void main_k(const float* __restrict__ scores,
                                              const float* __restrict__ points,
                                              const float* __restrict__ ctrs,
                                              const uint32_t* __restrict__ ws,
                                              float* __restrict__ out) {
    const int b = blockIdx.y;
    const uint4 st = *reinterpret_cast<const uint4*>(ws + STATE_OFF + b * 4);
    const float T = __uint_as_float(st.x);
    const bool eAll = (st.z == st.y);  // E == R: all equals selected

    const int p0 = blockIdx.x * 1024 + threadIdx.x * 4;
    if (p0 >= NPTS) return;

    const float* P = points + ((size_t)b * NPTS + p0) * 3;
    const float4 a = *reinterpret_cast<const float4*>(P);
    const float4 c4 = *reinterpret_cast<const float4*>(P + 4);
    const float4 e = *reinterpret_cast<const float4*>(P + 8);
    float px[4] = {a.x, a.w, c4.z, e.y};
    float py[4] = {a.y, c4.x, c4.w, e.z};
    float pz[4] = {a.z, c4.y, e.x, e.w};
    float m[4] = {1e30f, 1e30f, 1e30f, 1e30f};

    const float* C = ctrs + b * NBOX * 3;
#pragma unroll 16
    for (int k = 0; k < NBOX; ++k) {
        const float cx = C[3 * k + 0];
        const float cy = C[3 * k + 1];
        const float cz = C[3 * k + 2];
#pragma unroll
        for (int j = 0; j < 4; ++j) {
            float dx = px[j] - cx;
            float dy = py[j] - cy;
            float dz = pz[j] - cz;
            float d2 = fmaf(dz, dz, fmaf(dy, dy, dx * dx));
            m[j] = fminf(m[j], d2);
        }
    }

    const float4 sv = *reinterpret_cast<const float4*>(scores + (size_t)b * NPTS + p0);
    const float s[4] = {sv.x, sv.y, sv.z, sv.w};
    float pr[4], ls[4];
#pragma unroll
    for (int j = 0; j < 4; ++j) {
        bool gt;
        if (m[j] < C_LO) gt = true;
        else if (m[j] >= C_HI) gt = false;
        else gt = exact_gt(px[j], py[j], pz[j], C);  // rare boundary band
        const bool sm = eAll ? (s[j] >= T) : (s[j] > T);
        pr[j] = (gt || sm) ? 1.0f : 0.0f;
        const float x = gt ? -s[j] : s[j];
        ls[j] = fmaxf(x, 0.0f) + log1pf(expf(-fabsf(x)));
    }
    float* o0 = out + (size_t)b * NPTS + p0;
    float* o1 = out + (size_t)BB * NPTS + (size_t)b * NPTS + p0;
    *reinterpret_cast<float4*>(o0) = make_float4(pr[0], pr[1], pr[2], pr[3]);
    *reinterpret_cast<float4*>(o1) = make_float4(ls[0], ls[1], ls[2], ls[3]);
}

// ---------- Tie fixup: mark first R index-ordered equals (rare path) ----------
__global__ __launch_bounds__(1024) void ties_k(const float* __restrict__ scores,
                                               const uint32_t* __restrict__ ws,
                                               float* __restrict__ out) {
    const int b = blockIdx.x;
    const uint4 st = *reinterpret_cast<const uint4*>(ws + STATE_OFF + b * 4);
    const uint32_t R = st.y, E = st.z;
    if (E == R) return;  // common case: main kernel already handled via s>=T? no: E==R handled by eAll
    const float T = __uint_as_float(st.x);
    __shared__ uint32_t wcnt[16];
    __shared__ uint32_t running;
    if (threadIdx.x == 0) running = 0;
    __syncthreads();
    const float* s = scores + (size_t)b * NPTS;
    for (int base = 0; base < NPTS; base += 1024) {
        const uint32_t r0 = running;
        if (r0 >= R) break;
        const int i = base + threadIdx.x;
        const bool eq = (i < NPTS) && (s[i] == T);
        const unsigned long long mask = __ballot(eq);
        const int wid = threadIdx.x >> 6;
        const int lane = threadIdx.x & 63;
        if (lane == 0) wcnt[wid] = (uint32_t)__popcll(mask);
        __syncthreads();
        uint32_t before = 0, total = 0;
        for (int w = 0; w < 16; ++w) {
            uint32_t c = wcnt[w];
            if (w < wid) before += c;
            total += c;
        }
        if (eq) {
            uint32_t rank = r0 + before +
                (uint32_t)__popcll(mask & ((1ull << lane) - 1ull));
            if (rank < R) out[(size_t)b * NPTS + i] = 1.0f;
        }
        __syncthreads();
        if (threadIdx.x == 0) running = r0 + total;
        __syncthreads();
    }
}

extern "C" void kernel_launch(void* const* d_in, const int* in_sizes, int n_in,
                              void* d_out, int out_size, void* d_ws, size_t ws_size,
                              hipStream_t stream) {
    const float* scores = (const float*)d_in[0];
    const float* points = (const float*)d_in[1];
    const float* ctrs   = (const float*)d_in[2];
    float* out = (float*)d_out;
    uint32_t* ws = (uint32_t*)d_ws;

    hipMemsetAsync(d_ws, 0, MEMSET_BYTES, stream);

    const dim3 gridP((NPTS + 1023) / 1024, BB);  // 98 x 16
    hist0_k<<<gridP, 256, 0, stream>>>(scores, ws);
    scan0_k<<<BB, 64, 0, stream>>>(ws);
    compact_k<<<gridP, 256, 0, stream>>>(scores, ws);
    finish_k<<<BB, 1024, 0, stream>>>(ws);
    main_k<<<gridP, 256, 0, stream>>>(scores, points, ctrs, ws, out);
    ties_k<<<BB, 1024, 0, stream>>>(scores, ws, out);
}

// Round 2
// 101.027 us; speedup vs baseline: 2.9932x; 2.9932x over previous
//
#include <hip/hip_runtime.h>
#include <hip/hip_bf16.h>
#include <stdint.h>

// Problem constants
#define BB 16
#define NPTS 100000
#define NBOX 64
#define KTOP 2048
#define THRF 0.2f            // (float)(8*0.01*2.5)
#define C_LO 0.0399999f      // band around 0.2f^2 for exact-path fallback
#define C_HI 0.0400001f

// Workspace layout (in uint32 words)
#define HIST0_OFF 0                    // BB*256
#define CNT_OFF   (BB*256)             // BB
#define STATE_OFF (BB*256 + 16)       // BB*4 (16B aligned)
#define LIST_OFF  (BB*256 + 16 + BB*4)
#define LIST_CAP  16384                // per-batch compacted capacity
#define MEMSET_BYTES (LIST_OFF * 4)

__device__ __forceinline__ uint32_t fmap(float f) {
    uint32_t b = __float_as_uint(f);
    return (b & 0x80000000u) ? ~b : (b | 0x80000000u);
}

// ---------- Pass 0: 256-bin MSB histogram per batch ----------
__global__ __launch_bounds__(256) void hist0_k(const float* __restrict__ scores,
                                               uint32_t* __restrict__ ws) {
    __shared__ uint32_t h[256];
    const int b = blockIdx.y;
    h[threadIdx.x] = 0;
    __syncthreads();
    const int p0 = blockIdx.x * 1024 + threadIdx.x * 4;
    if (p0 < NPTS) {
        const float4 v = *reinterpret_cast<const float4*>(scores + (size_t)b * NPTS + p0);
        atomicAdd(&h[fmap(v.x) >> 24], 1u);
        atomicAdd(&h[fmap(v.y) >> 24], 1u);
        atomicAdd(&h[fmap(v.z) >> 24], 1u);
        atomicAdd(&h[fmap(v.w) >> 24], 1u);
    }
    __syncthreads();
    uint32_t c = h[threadIdx.x];
    if (c) atomicAdd(&ws[HIST0_OFF + b * 256 + threadIdx.x], c);
}

// ---------- Scan pass-0 histogram: pick MSB bin ----------
__global__ __launch_bounds__(256) void scan0_k(uint32_t* __restrict__ ws) {
    __shared__ uint32_t h[256];
    const int b = blockIdx.x;
    h[threadIdx.x] = ws[HIST0_OFF + b * 256 + threadIdx.x];
    __syncthreads();
    if (threadIdx.x != 0) return;
    uint32_t cum = 0;
    int bin = 255;
    for (; bin >= 0; --bin) {
        uint32_t c = h[bin];
        if (cum + c >= KTOP) break;
        cum += c;
    }
    uint32_t* st = ws + STATE_OFF + b * 4;
    st[0] = (uint32_t)bin << 24;  // prefix
    st[1] = KTOP - cum;           // krem
}

// ---------- Compact elements matching MSB prefix (1 global atomic/block) ----------
__global__ __launch_bounds__(256) void compact_k(const float* __restrict__ scores,
                                                 uint32_t* __restrict__ ws) {
    __shared__ uint32_t lcnt, lbase;
    __shared__ uint32_t lbuf[1024];
    const int b = blockIdx.y;
    if (threadIdx.x == 0) lcnt = 0;
    __syncthreads();
    const uint32_t pref = ws[STATE_OFF + b * 4] >> 24;  // wave-uniform
    const int p0 = blockIdx.x * 1024 + threadIdx.x * 4;
    if (p0 < NPTS) {
        const float4 v = *reinterpret_cast<const float4*>(scores + (size_t)b * NPTS + p0);
        uint32_t u[4] = {fmap(v.x), fmap(v.y), fmap(v.z), fmap(v.w)};
#pragma unroll
        for (int j = 0; j < 4; ++j) {
            if ((u[j] >> 24) == pref) {
                uint32_t pos = atomicAdd(&lcnt, 1u);  // LDS atomic, ~tens per block
                lbuf[pos] = u[j];
            }
        }
    }
    __syncthreads();
    if (threadIdx.x == 0) lbase = atomicAdd(&ws[CNT_OFF + b], lcnt);
    __syncthreads();
    const uint32_t n = lcnt, base = lbase;
    uint32_t* list = ws + LIST_OFF + (size_t)b * LIST_CAP;
    for (uint32_t i = threadIdx.x; i < n; i += 256)
        if (base + i < LIST_CAP) list[base + i] = lbuf[i];
}

// ---------- Finish radix select (3 passes in LDS) ----------
__global__ __launch_bounds__(1024) void finish_k(uint32_t* __restrict__ ws) {
    const int b = blockIdx.x;
    __shared__ uint32_t h[256];
    __shared__ uint32_t sPrefix, sKrem, sE;
    uint32_t* st = ws + STATE_OFF + b * 4;
    if (threadIdx.x == 0) {
        sPrefix = st[0];
        sKrem = st[1];
        sE = 0;
    }
    __syncthreads();
    uint32_t cnt = ws[CNT_OFF + b];
    if (cnt > LIST_CAP) cnt = LIST_CAP;
    const uint32_t* list = ws + LIST_OFF + (size_t)b * LIST_CAP;

#pragma unroll 1
    for (int shift = 16; shift >= 0; shift -= 8) {
        for (int i = threadIdx.x; i < 256; i += 1024) h[i] = 0;
        __syncthreads();
        const uint32_t pref = sPrefix;
        for (uint32_t i = threadIdx.x; i < cnt; i += 1024) {
            uint32_t u = list[i];
            if ((u >> (shift + 8)) == (pref >> (shift + 8)))
                atomicAdd(&h[(u >> shift) & 255u], 1u);
        }
        __syncthreads();
        if (threadIdx.x == 0) {
            uint32_t cum = 0;
            int bin = 255;
            for (; bin >= 0; --bin) {
                uint32_t c = h[bin];
                if (cum + c >= sKrem) break;
                cum += c;
            }
            sPrefix |= (uint32_t)bin << shift;
            sKrem -= cum;
            if (shift == 0) sE = h[bin];
        }
        __syncthreads();
    }
    if (threadIdx.x == 0) {
        uint32_t u = sPrefix;
        uint32_t bits = (u & 0x80000000u) ? (u & 0x7fffffffu) : ~u;
        st[0] = bits;        // T as float bits
        st[1] = sKrem;       // R: # of equals to take
        st[2] = sE;          // E: # of equals present
        st[3] = KTOP - sKrem;
    }
}

// ---------- exact (numpy-bit-identical) gt check for one point ----------
__device__ __noinline__ bool exact_gt(float px, float py, float pz,
                                      const float* __restrict__ C) {
    bool hit = false;
#pragma unroll 1
    for (int k = 0; k < NBOX; ++k) {
        float dx = px - C[3 * k + 0];
        float dy = py - C[3 * k + 1];
        float dz = pz - C[3 * k + 2];
        float d2 = __fadd_rn(__fadd_rn(__fmul_rn(dx, dx), __fmul_rn(dy, dy)),
                             __fmul_rn(dz, dz));
        if (__fsqrt_rn(d2) < THRF) hit = true;
    }
    return hit;
}

// ---------- Main: gt mask + prune mask + losses ----------
__global__ __launch_bounds__(256) void main_k(const float* __restrict__ scores,
                                              const float* __restrict__ points,
                                              const float* __restrict__ ctrs,
                                              const uint32_t* __restrict__ ws,
                                              float* __restrict__ out) {
    const int b = blockIdx.y;
    const uint4 st = *reinterpret_cast<const uint4*>(ws + STATE_OFF + b * 4);
    const float T = __uint_as_float(st.x);
    const bool eAll = (st.z == st.y);  // E == R: all equals selected

    const int p0 = blockIdx.x * 1024 + threadIdx.x * 4;
    if (p0 >= NPTS) return;

    const float* P = points + ((size_t)b * NPTS + p0) * 3;
    const float4 a = *reinterpret_cast<const float4*>(P);
    const float4 c4 = *reinterpret_cast<const float4*>(P + 4);
    const float4 e = *reinterpret_cast<const float4*>(P + 8);
    float px[4] = {a.x, a.w, c4.z, e.y};
    float py[4] = {a.y, c4.x, c4.w, e.z};
    float pz[4] = {a.z, c4.y, e.x, e.w};
    float m[4] = {1e30f, 1e30f, 1e30f, 1e30f};

    const float* C = ctrs + b * NBOX * 3;
#pragma unroll 16
    for (int k = 0; k < NBOX; ++k) {
        const float cx = C[3 * k + 0];
        const float cy = C[3 * k + 1];
        const float cz = C[3 * k + 2];
#pragma unroll
        for (int j = 0; j < 4; ++j) {
            float dx = px[j] - cx;
            float dy = py[j] - cy;
            float dz = pz[j] - cz;
            float d2 = fmaf(dz, dz, fmaf(dy, dy, dx * dx));
            m[j] = fminf(m[j], d2);
        }
    }

    const float4 sv = *reinterpret_cast<const float4*>(scores + (size_t)b * NPTS + p0);
    const float s[4] = {sv.x, sv.y, sv.z, sv.w};
    float pr[4], ls[4];
#pragma unroll
    for (int j = 0; j < 4; ++j) {
        bool gt;
        if (m[j] < C_LO) gt = true;
        else if (m[j] >= C_HI) gt = false;
        else gt = exact_gt(px[j], py[j], pz[j], C);  // rare boundary band
        const bool sm = eAll ? (s[j] >= T) : (s[j] > T);
        pr[j] = (gt || sm) ? 1.0f : 0.0f;
        const float x = gt ? -s[j] : s[j];
        ls[j] = fmaxf(x, 0.0f) + log1pf(expf(-fabsf(x)));
    }
    float* o0 = out + (size_t)b * NPTS + p0;
    float* o1 = out + (size_t)BB * NPTS + (size_t)b * NPTS + p0;
    *reinterpret_cast<float4*>(o0) = make_float4(pr[0], pr[1], pr[2], pr[3]);
    *reinterpret_cast<float4*>(o1) = make_float4(ls[0], ls[1], ls[2], ls[3]);
}

// ---------- Tie fixup: mark first R index-ordered equals (rare path) ----------
__global__ __launch_bounds__(1024) void ties_k(const float* __restrict__ scores,
                                               const uint32_t* __restrict__ ws,
                                               float* __restrict__ out) {
    const int b = blockIdx.x;
    const uint4 st = *reinterpret_cast<const uint4*>(ws + STATE_OFF + b * 4);
    const uint32_t R = st.y, E = st.z;
    if (E == R) return;  // common case handled in main_k via eAll
    const float T = __uint_as_float(st.x);
    __shared__ uint32_t wcnt[16];
    __shared__ uint32_t running;
    if (threadIdx.x == 0) running = 0;
    __syncthreads();
    const float* s = scores + (size_t)b * NPTS;
    for (int base = 0; base < NPTS; base += 1024) {
        const uint32_t r0 = running;
        if (r0 >= R) break;
        const int i = base + threadIdx.x;
        const bool eq = (i < NPTS) && (s[i] == T);
        const unsigned long long mask = __ballot(eq);
        const int wid = threadIdx.x >> 6;
        const int lane = threadIdx.x & 63;
        if (lane == 0) wcnt[wid] = (uint32_t)__popcll(mask);
        __syncthreads();
        uint32_t before = 0, total = 0;
        for (int w = 0; w < 16; ++w) {
            uint32_t c = wcnt[w];
            if (w < wid) before += c;
            total += c;
        }
        if (eq) {
            uint32_t rank = r0 + before +
                (uint32_t)__popcll(mask & ((1ull << lane) - 1ull));
            if (rank < R) out[(size_t)b * NPTS + i] = 1.0f;
        }
        __syncthreads();
        if (threadIdx.x == 0) running = r0 + total;
        __syncthreads();
    }
}

extern "C" void kernel_launch(void* const* d_in, const int* in_sizes, int n_in,
                              void* d_out, int out_size, void* d_ws, size_t ws_size,
                              hipStream_t stream) {
    const float* scores = (const float*)d_in[0];
    const float* points = (const float*)d_in[1];
    const float* ctrs   = (const float*)d_in[2];
    float* out = (float*)d_out;
    uint32_t* ws = (uint32_t*)d_ws;

    hipMemsetAsync(d_ws, 0, MEMSET_BYTES, stream);

    const dim3 gridP((NPTS + 1023) / 1024, BB);  // 98 x 16
    hist0_k<<<gridP, 256, 0, stream>>>(scores, ws);
    scan0_k<<<BB, 256, 0, stream>>>(ws);
    compact_k<<<gridP, 256, 0, stream>>>(scores, ws);
    finish_k<<<BB, 1024, 0, stream>>>(ws);
    main_k<<<gridP, 256, 0, stream>>>(scores, points, ctrs, ws, out);
    ties_k<<<BB, 1024, 0, stream>>>(scores, ws, out);
}

// Round 3
// 95.122 us; speedup vs baseline: 3.1790x; 1.0621x over previous
//
#include <hip/hip_runtime.h>
#include <hip/hip_bf16.h>
#include <stdint.h>

// Problem constants
#define BB 16
#define NPTS 100000
#define NBOX 64
#define KTOP 2048
#define THRF 0.2f            // (float)(8*0.01*2.5)
#define C_LO 0.0399999f      // band around 0.2f^2 for exact-path fallback
#define C_HI 0.0400001f

#define HSLICES 98                       // blocks per batch in hist_k
// Workspace layout (uint32 words). No pre-zeroing needed anywhere.
#define HIST_OFF 0                       // BB * HSLICES * 256 words (plain stores)
#define STATE_OFF (BB * HSLICES * 256)   // BB * 2 words {T_bits, Istar}
#define LIST_CAP 6144                    // LDS candidate capacity (expect ~2.3k)

__device__ __forceinline__ uint32_t fmap(float f) {
    uint32_t b = __float_as_uint(f);
    return (b & 0x80000000u) ? ~b : (b | 0x80000000u);
}

// ---------- Pass 1: per-block 256-bin MSB histogram, private slice stores ----------
__global__ __launch_bounds__(256) void hist_k(const float* __restrict__ scores,
                                              uint32_t* __restrict__ ws) {
    __shared__ uint32_t h[256];
    const int b = blockIdx.y;
    h[threadIdx.x] = 0;
    __syncthreads();
    const int p0 = blockIdx.x * 1024 + threadIdx.x * 4;
    if (p0 < NPTS) {
        const float4 v = *reinterpret_cast<const float4*>(scores + (size_t)b * NPTS + p0);
        atomicAdd(&h[fmap(v.x) >> 24], 1u);
        atomicAdd(&h[fmap(v.y) >> 24], 1u);
        atomicAdd(&h[fmap(v.z) >> 24], 1u);
        atomicAdd(&h[fmap(v.w) >> 24], 1u);
    }
    __syncthreads();
    ws[HIST_OFF + ((size_t)(b * HSLICES + blockIdx.x)) * 256 + threadIdx.x] = h[threadIdx.x];
}

// ---------- Pass 2: one block per batch — scan, compact-to-LDS, radix finish, ties ----------
__global__ __launch_bounds__(1024) void select_k(const float* __restrict__ scores,
                                                 uint32_t* __restrict__ ws) {
    const int b = blockIdx.x;
    const int tid = threadIdx.x;
    __shared__ uint32_t hsum[4][256];
    __shared__ uint32_t hist[256];
    __shared__ uint32_t list[LIST_CAP];
    __shared__ uint32_t lcnt;
    __shared__ uint32_t sPrefix, sKrem, sE, sIstar, sRun;

    // reduce 98 per-block slices -> 256-bin histogram
    {
        const int g = tid >> 8, t = tid & 255;
        const int s0 = g * 25, s1 = (g == 3) ? HSLICES : (g + 1) * 25;
        uint32_t acc = 0;
        for (int s = s0; s < s1; ++s)
            acc += ws[HIST_OFF + ((size_t)(b * HSLICES + s)) * 256 + t];
        hsum[g][t] = acc;
    }
    if (tid == 0) lcnt = 0;
    __syncthreads();
    if (tid < 256) hist[tid] = hsum[0][tid] + hsum[1][tid] + hsum[2][tid] + hsum[3][tid];
    __syncthreads();
    if (tid == 0) {
        uint32_t cum = 0;
        int bin = 255;
        for (; bin >= 0; --bin) {
            uint32_t c = hist[bin];
            if (cum + c >= KTOP) break;
            cum += c;
        }
        sPrefix = (uint32_t)bin << 24;
        sKrem = KTOP - cum;
    }
    __syncthreads();

    // compact candidates matching MSB byte into LDS
    {
        const uint32_t pref = sPrefix >> 24;
        const float* s = scores + (size_t)b * NPTS;
        for (int i4 = tid; i4 < NPTS / 4; i4 += 1024) {
            const float4 v = *reinterpret_cast<const float4*>(s + i4 * 4);
            uint32_t u[4] = {fmap(v.x), fmap(v.y), fmap(v.z), fmap(v.w)};
#pragma unroll
            for (int j = 0; j < 4; ++j) {
                if ((u[j] >> 24) == pref) {
                    uint32_t pos = atomicAdd(&lcnt, 1u);
                    if (pos < LIST_CAP) list[pos] = u[j];
                }
            }
        }
    }
    __syncthreads();
    uint32_t cnt = lcnt;
    if (cnt > LIST_CAP) cnt = LIST_CAP;

    // 3 radix passes over the LDS list
#pragma unroll 1
    for (int shift = 16; shift >= 0; shift -= 8) {
        if (tid < 256) hist[tid] = 0;
        __syncthreads();
        const uint32_t pref = sPrefix;
        for (uint32_t i = tid; i < cnt; i += 1024) {
            uint32_t u = list[i];
            if ((u >> (shift + 8)) == (pref >> (shift + 8)))
                atomicAdd(&hist[(u >> shift) & 255u], 1u);
        }
        __syncthreads();
        if (tid == 0) {
            uint32_t cum = 0;
            int bin = 255;
            for (; bin >= 0; --bin) {
                uint32_t c = hist[bin];
                if (cum + c >= sKrem) break;
                cum += c;
            }
            sPrefix |= (uint32_t)bin << shift;
            sKrem -= cum;
            if (shift == 0) sE = hist[bin];
        }
        __syncthreads();
    }

    const uint32_t R = sKrem, E = sE;
    const uint32_t u = sPrefix;
    const uint32_t tbits = (u & 0x80000000u) ? (u & 0x7fffffffu) : ~u;
    if (tid == 0) sIstar = NPTS;

    if (E != R) {
        // rare: find global index of the (R+1)-th element equal to T (0-based rank R)
        __shared__ uint32_t wcnt[16];
        const float T = __uint_as_float(tbits);
        if (tid == 0) sRun = 0;
        __syncthreads();
        const float* s = scores + (size_t)b * NPTS;
        const int wid = tid >> 6, lane = tid & 63;
        for (int base = 0; base < NPTS; base += 1024) {
            const uint32_t r0 = sRun;
            if (r0 > R) break;
            const int i = base + tid;
            const bool eq = (i < NPTS) && (s[i] == T);
            const unsigned long long mask = __ballot(eq);
            if (lane == 0) wcnt[wid] = (uint32_t)__popcll(mask);
            __syncthreads();
            uint32_t before = 0, total = 0;
            for (int w = 0; w < 16; ++w) {
                uint32_t c = wcnt[w];
                if (w < wid) before += c;
                total += c;
            }
            if (eq) {
                uint32_t rank = r0 + before +
                    (uint32_t)__popcll(mask & ((1ull << lane) - 1ull));
                if (rank == R) sIstar = (uint32_t)i;
            }
            __syncthreads();
            if (tid == 0) sRun = r0 + total;
            __syncthreads();
        }
    }
    __syncthreads();
    if (tid == 0) {
        uint32_t* st = ws + STATE_OFF + b * 2;
        st[0] = tbits;   // threshold T as float bits
        st[1] = sIstar;  // ties: s==T taken iff idx < Istar (NPTS when all taken)
    }
}

// ---------- exact (numpy-bit-identical) gt check for one point ----------
__device__ __noinline__ bool exact_gt(float px, float py, float pz,
                                      const float* __restrict__ C) {
    bool hit = false;
#pragma unroll 1
    for (int k = 0; k < NBOX; ++k) {
        float dx = px - C[3 * k + 0];
        float dy = py - C[3 * k + 1];
        float dz = pz - C[3 * k + 2];
        float d2 = __fadd_rn(__fadd_rn(__fmul_rn(dx, dx), __fmul_rn(dy, dy)),
                             __fmul_rn(dz, dz));
        if (__fsqrt_rn(d2) < THRF) hit = true;
    }
    return hit;
}

// ---------- Main: gt mask + prune mask + losses ----------
__global__ __launch_bounds__(256) void main_k(const float* __restrict__ scores,
                                              const float* __restrict__ points,
                                              const float* __restrict__ ctrs,
                                              const uint32_t* __restrict__ ws,
                                              float* __restrict__ out) {
    const int b = blockIdx.y;
    const uint32_t* st = ws + STATE_OFF + b * 2;
    const float T = __uint_as_float(st[0]);
    const uint32_t Istar = st[1];

    const int p0 = blockIdx.x * 1024 + threadIdx.x * 4;
    if (p0 >= NPTS) return;

    const float* P = points + ((size_t)b * NPTS + p0) * 3;
    const float4 a = *reinterpret_cast<const float4*>(P);
    const float4 c4 = *reinterpret_cast<const float4*>(P + 4);
    const float4 e = *reinterpret_cast<const float4*>(P + 8);
    float px[4] = {a.x, a.w, c4.z, e.y};
    float py[4] = {a.y, c4.x, c4.w, e.z};
    float pz[4] = {a.z, c4.y, e.x, e.w};
    float m[4] = {1e30f, 1e30f, 1e30f, 1e30f};

    const float* C = ctrs + b * NBOX * 3;
#pragma unroll 16
    for (int k = 0; k < NBOX; ++k) {
        const float cx = C[3 * k + 0];
        const float cy = C[3 * k + 1];
        const float cz = C[3 * k + 2];
#pragma unroll
        for (int j = 0; j < 4; ++j) {
            float dx = px[j] - cx;
            float dy = py[j] - cy;
            float dz = pz[j] - cz;
            float d2 = fmaf(dz, dz, fmaf(dy, dy, dx * dx));
            m[j] = fminf(m[j], d2);
        }
    }

    const float4 sv = *reinterpret_cast<const float4*>(scores + (size_t)b * NPTS + p0);
    const float s[4] = {sv.x, sv.y, sv.z, sv.w};
    float pr[4], ls[4];
#pragma unroll
    for (int j = 0; j < 4; ++j) {
        bool gt;
        if (m[j] < C_LO) gt = true;
        else if (m[j] >= C_HI) gt = false;
        else gt = exact_gt(px[j], py[j], pz[j], C);  // rare boundary band
        const bool sm = (s[j] > T) || (s[j] == T && (uint32_t)(p0 + j) < Istar);
        pr[j] = (gt || sm) ? 1.0f : 0.0f;
        const float x = gt ? -s[j] : s[j];
        ls[j] = fmaxf(x, 0.0f) + log1pf(expf(-fabsf(x)));
    }
    float* o0 = out + (size_t)b * NPTS + p0;
    float* o1 = out + (size_t)BB * NPTS + (size_t)b * NPTS + p0;
    *reinterpret_cast<float4*>(o0) = make_float4(pr[0], pr[1], pr[2], pr[3]);
    *reinterpret_cast<float4*>(o1) = make_float4(ls[0], ls[1], ls[2], ls[3]);
}

extern "C" void kernel_launch(void* const* d_in, const int* in_sizes, int n_in,
                              void* d_out, int out_size, void* d_ws, size_t ws_size,
                              hipStream_t stream) {
    const float* scores = (const float*)d_in[0];
    const float* points = (const float*)d_in[1];
    const float* ctrs   = (const float*)d_in[2];
    float* out = (float*)d_out;
    uint32_t* ws = (uint32_t*)d_ws;

    const dim3 gridP(HSLICES, BB);  // 98 x 16
    hist_k<<<gridP, 256, 0, stream>>>(scores, ws);
    select_k<<<BB, 1024, 0, stream>>>(scores, ws);
    main_k<<<gridP, 256, 0, stream>>>(scores, points, ctrs, ws, out);
}

// Round 4
// 68.707 us; speedup vs baseline: 4.4012x; 1.3844x over previous
//
#include <hip/hip_runtime.h>
#include <hip/hip_bf16.h>
#include <stdint.h>

// Problem constants
#define BB 16
#define NPTS 100000
#define NBOX 64
#define KTOP 2048
#define THRF 0.2f            // (float)(8*0.01*2.5)
// band around 0.2^2 for exact-path fallback; fast path error bound ~5e-6
#define C_LO 0.039984f
#define C_HI 0.040016f

#define HSLICES 98                       // blocks per batch in hist_k
// Workspace layout (uint32 words). No pre-zeroing needed anywhere.
#define HIST_OFF 0                       // BB * HSLICES * 256 words (plain stores)
#define STATE_OFF (BB * HSLICES * 256)   // BB * 2 words {T_bits, Istar}
#define LIST_CAP 6144                    // LDS candidate capacity (expect ~2.3k)

__device__ __forceinline__ uint32_t fmap(float f) {
    uint32_t b = __float_as_uint(f);
    return (b & 0x80000000u) ? ~b : (b | 0x80000000u);
}

// ---------- Pass 1: per-block MSB histogram (4 per-wave sub-hists) ----------
__global__ __launch_bounds__(256) void hist_k(const float* __restrict__ scores,
                                              uint32_t* __restrict__ ws) {
    __shared__ uint32_t h[4][256];
    const int b = blockIdx.y;
    const int w = threadIdx.x >> 6;
#pragma unroll
    for (int j = 0; j < 4; ++j) h[j][threadIdx.x] = 0;
    __syncthreads();
    const int p0 = blockIdx.x * 1024 + threadIdx.x * 4;
    if (p0 < NPTS) {
        const float4 v = *reinterpret_cast<const float4*>(scores + (size_t)b * NPTS + p0);
        atomicAdd(&h[w][fmap(v.x) >> 24], 1u);
        atomicAdd(&h[w][fmap(v.y) >> 24], 1u);
        atomicAdd(&h[w][fmap(v.z) >> 24], 1u);
        atomicAdd(&h[w][fmap(v.w) >> 24], 1u);
    }
    __syncthreads();
    ws[HIST_OFF + ((size_t)(b * HSLICES + blockIdx.x)) * 256 + threadIdx.x] =
        h[0][threadIdx.x] + h[1][threadIdx.x] + h[2][threadIdx.x] + h[3][threadIdx.x];
}

// Parallel suffix-sum bin selection: pick largest bin with S[bin] >= target.
// All 1024 threads must call (barriers). Writes *outBin/*outKrem (and *outE).
__device__ __forceinline__ void suffix_select(const uint32_t* __restrict__ hist,
                                              uint32_t* __restrict__ S, int tid,
                                              uint32_t target,
                                              volatile uint32_t* outBin,
                                              volatile uint32_t* outKrem,
                                              volatile uint32_t* outE) {
    if (tid < 256) S[tid] = hist[tid];
    __syncthreads();
#pragma unroll
    for (int off = 1; off < 256; off <<= 1) {
        uint32_t add = 0;
        if (tid < 256 && tid + off < 256) add = S[tid + off];
        __syncthreads();
        if (tid < 256) S[tid] += add;
        __syncthreads();
    }
    if (tid < 256) {
        const uint32_t St = S[tid];
        const uint32_t Sn = (tid == 255) ? 0u : S[tid + 1];
        if (St >= target && Sn < target) {  // unique t
            *outBin = (uint32_t)tid;
            *outKrem = target - Sn;
            if (outE) *outE = St - Sn;
        }
    }
    __syncthreads();
}

// ---------- Pass 2: one block/batch — scan, compact-to-LDS, radix finish, ties ----------
__global__ __launch_bounds__(1024) void select_k(const float* __restrict__ scores,
                                                 uint32_t* __restrict__ ws) {
    const int b = blockIdx.x;
    const int tid = threadIdx.x;
    __shared__ uint32_t hsum[4][256];
    __shared__ uint32_t hist[256];
    __shared__ uint32_t S[256];
    __shared__ uint32_t list[LIST_CAP];
    __shared__ uint32_t lcnt;
    __shared__ uint32_t sBin, sKrem, sE, sIstar, sRun;

    // reduce 98 per-block slices -> 256-bin histogram
    {
        const int g = tid >> 8, t = tid & 255;
        const int s0 = g * 25, s1 = (g == 3) ? HSLICES : (g + 1) * 25;
        uint32_t acc = 0;
        for (int s = s0; s < s1; ++s)
            acc += ws[HIST_OFF + ((size_t)(b * HSLICES + s)) * 256 + t];
        hsum[g][t] = acc;
    }
    if (tid == 0) { lcnt = 0; sIstar = NPTS; }
    __syncthreads();
    if (tid < 256) hist[tid] = hsum[0][tid] + hsum[1][tid] + hsum[2][tid] + hsum[3][tid];
    __syncthreads();

    suffix_select(hist, S, tid, KTOP, &sBin, &sKrem, nullptr);
    uint32_t prefix = sBin << 24;

    // compact candidates matching MSB byte into LDS (wave-aggregated atomics)
    {
        const uint32_t pref = prefix >> 24;
        const int lane = tid & 63;
        const unsigned long long lmask = (1ull << lane) - 1ull;
        const float* s = scores + (size_t)b * NPTS;
        for (int i4 = tid; i4 < NPTS / 4; i4 += 1024) {
            const float4 v = *reinterpret_cast<const float4*>(s + i4 * 4);
            uint32_t u[4] = {fmap(v.x), fmap(v.y), fmap(v.z), fmap(v.w)};
#pragma unroll
            for (int j = 0; j < 4; ++j) {
                const bool m = (u[j] >> 24) == pref;
                const unsigned long long mask = __ballot(m);
                if (mask) {
                    uint32_t base = 0;
                    if (lane == 0) base = atomicAdd(&lcnt, (uint32_t)__popcll(mask));
                    base = __shfl(base, 0);
                    if (m) {
                        const uint32_t pos = base + (uint32_t)__popcll(mask & lmask);
                        if (pos < LIST_CAP) list[pos] = u[j];
                    }
                }
            }
        }
    }
    __syncthreads();
    uint32_t cnt = lcnt;
    if (cnt > LIST_CAP) cnt = LIST_CAP;

    // 3 radix passes over the LDS list
#pragma unroll 1
    for (int shift = 16; shift >= 0; shift -= 8) {
        if (tid < 256) hist[tid] = 0;
        __syncthreads();
        const uint32_t hi = prefix >> (shift + 8);
        for (uint32_t i = tid; i < cnt; i += 1024) {
            const uint32_t u = list[i];
            if ((u >> (shift + 8)) == hi)
                atomicAdd(&hist[(u >> shift) & 255u], 1u);
        }
        __syncthreads();
        const uint32_t target = sKrem;
        suffix_select(hist, S, tid, target, &sBin, &sKrem,
                      (shift == 0) ? &sE : nullptr);
        prefix |= sBin << shift;
    }

    const uint32_t R = sKrem, E = sE;
    const uint32_t tbits = (prefix & 0x80000000u) ? (prefix & 0x7fffffffu) : ~prefix;

    if (E != R) {
        // rare: find global index of the 0-based rank-R element equal to T
        __shared__ uint32_t wcnt[16];
        const float T = __uint_as_float(tbits);
        if (tid == 0) sRun = 0;
        __syncthreads();
        const float* s = scores + (size_t)b * NPTS;
        const int wid = tid >> 6, lane = tid & 63;
        for (int base = 0; base < NPTS; base += 1024) {
            const uint32_t r0 = sRun;
            if (r0 > R) break;
            const int i = base + tid;
            const bool eq = (i < NPTS) && (s[i] == T);
            const unsigned long long mask = __ballot(eq);
            if (lane == 0) wcnt[wid] = (uint32_t)__popcll(mask);
            __syncthreads();
            uint32_t before = 0, total = 0;
            for (int w = 0; w < 16; ++w) {
                const uint32_t c = wcnt[w];
                if (w < wid) before += c;
                total += c;
            }
            if (eq) {
                const uint32_t rank = r0 + before +
                    (uint32_t)__popcll(mask & ((1ull << lane) - 1ull));
                if (rank == R) sIstar = (uint32_t)i;
            }
            __syncthreads();
            if (tid == 0) sRun = r0 + total;
            __syncthreads();
        }
        __syncthreads();
    }
    if (tid == 0) {
        uint32_t* st = ws + STATE_OFF + b * 2;
        st[0] = tbits;   // threshold T as float bits
        st[1] = sIstar;  // ties: s==T taken iff idx < Istar (NPTS when all taken)
    }
}

// ---------- exact (numpy-bit-identical) gt check for one point ----------
__device__ __noinline__ bool exact_gt(float px, float py, float pz,
                                      const float* __restrict__ C) {
    bool hit = false;
#pragma unroll 1
    for (int k = 0; k < NBOX; ++k) {
        float dx = px - C[3 * k + 0];
        float dy = py - C[3 * k + 1];
        float dz = pz - C[3 * k + 2];
        float d2 = __fadd_rn(__fadd_rn(__fmul_rn(dx, dx), __fmul_rn(dy, dy)),
                             __fmul_rn(dz, dz));
        if (__fsqrt_rn(d2) < THRF) hit = true;
    }
    return hit;
}

// ---------- Main: gt mask + prune mask + losses ----------
__global__ __launch_bounds__(256) void main_k(const float* __restrict__ scores,
                                              const float* __restrict__ points,
                                              const float* __restrict__ ctrs,
                                              const uint32_t* __restrict__ ws,
                                              float* __restrict__ out) {
    const int b = blockIdx.y;
    const uint32_t* st = ws + STATE_OFF + b * 2;
    const float T = __uint_as_float(st[0]);
    const uint32_t Istar = st[1];

    const int p0 = blockIdx.x * 1024 + threadIdx.x * 4;
    if (p0 >= NPTS) return;

    const float* P = points + ((size_t)b * NPTS + p0) * 3;
    const float4 a = *reinterpret_cast<const float4*>(P);
    const float4 c4 = *reinterpret_cast<const float4*>(P + 4);
    const float4 e = *reinterpret_cast<const float4*>(P + 8);
    const float px[4] = {a.x, a.w, c4.z, e.y};
    const float py[4] = {a.y, c4.x, c4.w, e.z};
    const float pz[4] = {a.z, c4.y, e.x, e.w};
    // d^2 = p.p + (c.c - 2 p.c); min commutes with +p.p (per-point constant)
    float m2[4] = {1e30f, 1e30f, 1e30f, 1e30f};

    const float* C = ctrs + b * NBOX * 3;
#pragma unroll 16
    for (int k = 0; k < NBOX; ++k) {
        const float cx = C[3 * k + 0];
        const float cy = C[3 * k + 1];
        const float cz = C[3 * k + 2];
        const float cc = fmaf(cx, cx, fmaf(cy, cy, cz * cz));
        const float m2x = -2.0f * cx, m2y = -2.0f * cy, m2z = -2.0f * cz;
#pragma unroll
        for (int j = 0; j < 4; ++j) {
            const float t = fmaf(m2x, px[j], fmaf(m2y, py[j], fmaf(m2z, pz[j], cc)));
            m2[j] = fminf(m2[j], t);
        }
    }

    const float4 sv = *reinterpret_cast<const float4*>(scores + (size_t)b * NPTS + p0);
    const float s[4] = {sv.x, sv.y, sv.z, sv.w};
    float pr[4], ls[4];
#pragma unroll
    for (int j = 0; j < 4; ++j) {
        const float pp = fmaf(px[j], px[j], fmaf(py[j], py[j], pz[j] * pz[j]));
        const float m = pp + m2[j];
        bool gt;
        if (m < C_LO) gt = true;
        else if (m >= C_HI) gt = false;
        else gt = exact_gt(px[j], py[j], pz[j], C);  // rare boundary band
        const bool sm = (s[j] > T) || (s[j] == T && (uint32_t)(p0 + j) < Istar);
        pr[j] = (gt || sm) ? 1.0f : 0.0f;
        const float x = gt ? -s[j] : s[j];
        ls[j] = fmaxf(x, 0.0f) + log1pf(expf(-fabsf(x)));
    }
    float* o0 = out + (size_t)b * NPTS + p0;
    float* o1 = out + (size_t)BB * NPTS + (size_t)b * NPTS + p0;
    *reinterpret_cast<float4*>(o0) = make_float4(pr[0], pr[1], pr[2], pr[3]);
    *reinterpret_cast<float4*>(o1) = make_float4(ls[0], ls[1], ls[2], ls[3]);
}

extern "C" void kernel_launch(void* const* d_in, const int* in_sizes, int n_in,
                              void* d_out, int out_size, void* d_ws, size_t ws_size,
                              hipStream_t stream) {
    const float* scores = (const float*)d_in[0];
    const float* points = (const float*)d_in[1];
    const float* ctrs   = (const float*)d_in[2];
    float* out = (float*)d_out;
    uint32_t* ws = (uint32_t*)d_ws;

    const dim3 gridP(HSLICES, BB);  // 98 x 16
    hist_k<<<gridP, 256, 0, stream>>>(scores, ws);
    select_k<<<BB, 1024, 0, stream>>>(scores, ws);
    main_k<<<gridP, 256, 0, stream>>>(scores, points, ctrs, ws, out);
}

// Round 5
// 52.145 us; speedup vs baseline: 5.7991x; 1.3176x over previous
//
#include <hip/hip_runtime.h>
#include <hip/hip_bf16.h>
#include <stdint.h>

// Problem constants
#define BB 16
#define NPTS 100000
#define NBOX 64
#define KTOP 2048
#define THRF 0.2f            // (float)(8*0.01*2.5)
// band around 0.2^2 for exact-path fallback; fast path error bound ~5e-6
#define C_LO 0.039984f
#define C_HI 0.040016f

#define HSLICES 98
#define SLICE_PTS 1024

// Workspace layout (uint32 words). No pre-zeroing needed.
#define VALS_OFF  0                                   // BB*HSLICES*1024 bucketed values
#define HISTG_OFF (BB * HSLICES * 1024)               // BB*HSLICES*256 per-slice hist
#define PREFG_OFF (HISTG_OFF + BB * HSLICES * 256)    // BB*HSLICES*256 per-slice excl prefix
#define STATE_OFF (PREFG_OFF + BB * HSLICES * 256)    // BB*2 {T_bits, Istar}
#define LIST_CAP 8192

__device__ __forceinline__ uint32_t fmap(float f) {
    uint32_t b = __float_as_uint(f);
    return (b & 0x80000000u) ? ~b : (b | 0x80000000u);
}

// ---------- Pass 1: per-slice LDS counting sort by MSB byte ----------
__global__ __launch_bounds__(256) void bucket_k(const float* __restrict__ scores,
                                                uint32_t* __restrict__ ws) {
    __shared__ uint32_t wh[4][256];    // per-wave sub-hists
    __shared__ uint32_t htmp[256];     // combined hist
    __shared__ uint32_t excl[256];     // exclusive prefix
    __shared__ uint32_t wcur[4][256];  // per-wave scatter cursors
    __shared__ uint32_t sorted[SLICE_PTS];
    const int b = blockIdx.y, sl = blockIdx.x;
    const int tid = threadIdx.x, w = tid >> 6, lane = tid & 63;
#pragma unroll
    for (int j = 0; j < 4; ++j) wh[j][tid] = 0;
    __syncthreads();
    const int p0 = sl * SLICE_PTS + tid * 4;
    uint32_t u[4];
    const bool valid = p0 < NPTS;
    if (valid) {
        const float4 v = *reinterpret_cast<const float4*>(scores + (size_t)b * NPTS + p0);
        u[0] = fmap(v.x); u[1] = fmap(v.y); u[2] = fmap(v.z); u[3] = fmap(v.w);
#pragma unroll
        for (int j = 0; j < 4; ++j) atomicAdd(&wh[w][u[j] >> 24], 1u);
    }
    __syncthreads();
    const uint32_t c0 = wh[0][tid], c1 = wh[1][tid], c2 = wh[2][tid], c3 = wh[3][tid];
    const uint32_t ht = c0 + c1 + c2 + c3;
    htmp[tid] = ht;
    __syncthreads();
    if (tid < 64) {  // wave-0 exclusive prefix scan over 256 bins, 4/lane
        const uint32_t v0 = htmp[4*tid], v1 = htmp[4*tid+1], v2 = htmp[4*tid+2], v3 = htmp[4*tid+3];
        const uint32_t lt = v0 + v1 + v2 + v3;
        uint32_t x = lt;
#pragma unroll
        for (int off = 1; off < 64; off <<= 1) {
            const uint32_t y = __shfl_up(x, off);
            if (lane >= off) x += y;
        }
        const uint32_t ex = x - lt;
        excl[4*tid] = ex; excl[4*tid+1] = ex + v0;
        excl[4*tid+2] = ex + v0 + v1; excl[4*tid+3] = ex + v0 + v1 + v2;
    }
    __syncthreads();
    const uint32_t e = excl[tid];
    wcur[0][tid] = e;
    wcur[1][tid] = e + c0;
    wcur[2][tid] = e + c0 + c1;
    wcur[3][tid] = e + c0 + c1 + c2;
    const size_t sb = ((size_t)(b * HSLICES + sl)) * 256;
    ws[HISTG_OFF + sb + tid] = ht;
    ws[PREFG_OFF + sb + tid] = e;
    __syncthreads();
    if (valid) {
#pragma unroll
        for (int j = 0; j < 4; ++j) {
            const uint32_t pos = atomicAdd(&wcur[w][u[j] >> 24], 1u);
            sorted[pos] = u[j];
        }
    }
    __syncthreads();
    const int n = min(SLICE_PTS, NPTS - sl * SLICE_PTS);
    uint32_t* gv = ws + VALS_OFF + ((size_t)(b * HSLICES + sl)) * SLICE_PTS;
    for (int i = tid; i < n; i += 256) gv[i] = sorted[i];
}

// Wave-0 suffix-select on a 256-bin LDS hist: largest bin with suffix_sum >= target.
// All threads of the block must call (barriers inside).
__device__ __forceinline__ void wave_select(const uint32_t* __restrict__ h,
                                            uint32_t* __restrict__ pf,
                                            int tid, int lane, uint32_t target,
                                            uint32_t* sBin, uint32_t* sKrem,
                                            uint32_t* sE, uint32_t* sTot) {
    __syncthreads();  // h ready
    if (tid < 64) {
        const uint32_t v0 = h[4*tid], v1 = h[4*tid+1], v2 = h[4*tid+2], v3 = h[4*tid+3];
        const uint32_t lt = v0 + v1 + v2 + v3;
        uint32_t x = lt;
#pragma unroll
        for (int off = 1; off < 64; off <<= 1) {
            const uint32_t y = __shfl_up(x, off);
            if (lane >= off) x += y;
        }
        const uint32_t ex = x - lt;
        pf[4*tid] = ex; pf[4*tid+1] = ex + v0;
        pf[4*tid+2] = ex + v0 + v1; pf[4*tid+3] = ex + v0 + v1 + v2;
        if (tid == 63) *sTot = x;
    }
    __syncthreads();
    if (tid < 256) {
        const uint32_t total = *sTot, lim = total - target;  // target>=1, total>=target
        const uint32_t pe = pf[tid];
        const uint32_t pe1 = (tid == 255) ? total : pf[tid + 1];
        if (pe <= lim && pe1 > lim) {  // unique interval containing lim
            *sBin = (uint32_t)tid;
            *sKrem = target - (total - pe1);
            *sE = pe1 - pe;
        }
    }
    __syncthreads();
}

// ---------- Pass 2: one block/batch — reduce, gather candidates, radix, ties ----------
__global__ __launch_bounds__(1024) void select_k(const float* __restrict__ scores,
                                                 uint32_t* __restrict__ ws) {
    const int b = blockIdx.x, tid = threadIdx.x, lane = tid & 63, wid = tid >> 6;
    __shared__ uint32_t hsum[4][256];
    __shared__ uint32_t hist[256];
    __shared__ uint32_t pf[256];
    __shared__ uint32_t lens[HSLICES], starts[HSLICES], outoff[HSLICES];
    __shared__ uint32_t list[LIST_CAP];
    __shared__ uint32_t sBin, sKrem, sE, sTot, sCnt, sIstar, sRun;

    // Phase A: reduce per-slice hists -> batch hist
    {
        const int g = tid >> 8, t = tid & 255;
        const int s0 = g * 25, s1 = (g == 3) ? HSLICES : (s0 + 25);
        uint32_t acc = 0;
        for (int s = s0; s < s1; ++s)
            acc += ws[HISTG_OFF + ((size_t)(b * HSLICES + s)) * 256 + t];
        hsum[g][t] = acc;
    }
    if (tid == 0) sIstar = NPTS;
    __syncthreads();
    if (tid < 256) hist[tid] = hsum[0][tid] + hsum[1][tid] + hsum[2][tid] + hsum[3][tid];
    wave_select(hist, pf, tid, lane, KTOP, &sBin, &sKrem, &sE, &sTot);
    uint32_t prefix = sBin << 24;
    const uint32_t beta = sBin;

    // Phase B: gather boundary-bin candidates from bucketed slices
    if (tid < HSLICES) {
        const size_t sb = ((size_t)(b * HSLICES + tid)) * 256;
        lens[tid] = ws[HISTG_OFF + sb + beta];
        starts[tid] = ws[PREFG_OFF + sb + beta];
    }
    __syncthreads();
    if (tid < 64) {  // exclusive scan of 98 lens, 2/lane
        uint32_t a = 0, b2 = 0;
        if (tid < 49) { a = lens[2*tid]; if (2*tid + 1 < HSLICES) b2 = lens[2*tid+1]; }
        const uint32_t lt = a + b2;
        uint32_t x = lt;
#pragma unroll
        for (int off = 1; off < 64; off <<= 1) {
            const uint32_t y = __shfl_up(x, off);
            if (lane >= off) x += y;
        }
        const uint32_t ex = x - lt;
        if (tid < 49) { outoff[2*tid] = ex; if (2*tid + 1 < HSLICES) outoff[2*tid+1] = ex + a; }
        if (tid == 63) sCnt = x;
    }
    __syncthreads();
    uint32_t cnt = sCnt;
    if (cnt > LIST_CAP) cnt = LIST_CAP;
    for (int s = wid; s < HSLICES; s += 16) {
        const uint32_t len = lens[s], st = starts[s], oo = outoff[s];
        const uint32_t* gv = ws + VALS_OFF + ((size_t)(b * HSLICES + s)) * SLICE_PTS + st;
        for (uint32_t j = lane; j < len; j += 64) {
            const uint32_t o = oo + j;
            if (o < LIST_CAP) list[o] = gv[j];
        }
    }

    // Phase C: 3 radix passes over the candidate list
#pragma unroll 1
    for (int shift = 16; shift >= 0; shift -= 8) {
        __syncthreads();  // list / previous pass done
        if (tid < 256) hist[tid] = 0;
        __syncthreads();
        const uint32_t hi = prefix >> (shift + 8);
        for (uint32_t i = tid; i < cnt; i += 1024) {
            const uint32_t u = list[i];
            if ((u >> (shift + 8)) == hi)
                atomicAdd(&hist[(u >> shift) & 255u], 1u);
        }
        const uint32_t target = sKrem;
        wave_select(hist, pf, tid, lane, target, &sBin, &sKrem, &sE, &sTot);
        prefix |= sBin << shift;
    }

    const uint32_t R = sKrem, E = sE;
    const uint32_t tbits = (prefix & 0x80000000u) ? (prefix & 0x7fffffffu) : ~prefix;

    if (E != R) {
        // rare: find global index of the 0-based rank-R element equal to T
        __shared__ uint32_t wcnt[16];
        const float T = __uint_as_float(tbits);
        if (tid == 0) sRun = 0;
        __syncthreads();
        const float* s = scores + (size_t)b * NPTS;
        for (int base = 0; base < NPTS; base += 1024) {
            const uint32_t r0 = sRun;
            if (r0 > R) break;
            const int i = base + tid;
            const bool eq = (i < NPTS) && (s[i] == T);
            const unsigned long long mask = __ballot(eq);
            if (lane == 0) wcnt[wid] = (uint32_t)__popcll(mask);
            __syncthreads();
            uint32_t before = 0, total = 0;
            for (int w = 0; w < 16; ++w) {
                const uint32_t c = wcnt[w];
                if (w < wid) before += c;
                total += c;
            }
            if (eq) {
                const uint32_t rank = r0 + before +
                    (uint32_t)__popcll(mask & ((1ull << lane) - 1ull));
                if (rank == R) sIstar = (uint32_t)i;
            }
            __syncthreads();
            if (tid == 0) sRun = r0 + total;
            __syncthreads();
        }
        __syncthreads();
    }
    if (tid == 0) {
        uint32_t* st = ws + STATE_OFF + b * 2;
        st[0] = tbits;   // threshold T as float bits
        st[1] = sIstar;  // ties: s==T taken iff idx < Istar
    }
}

// ---------- exact (numpy-bit-identical) gt check for one point ----------
__device__ __noinline__ bool exact_gt(float px, float py, float pz,
                                      const float* __restrict__ C) {
    bool hit = false;
#pragma unroll 1
    for (int k = 0; k < NBOX; ++k) {
        float dx = px - C[3 * k + 0];
        float dy = py - C[3 * k + 1];
        float dz = pz - C[3 * k + 2];
        float d2 = __fadd_rn(__fadd_rn(__fmul_rn(dx, dx), __fmul_rn(dy, dy)),
                             __fmul_rn(dz, dz));
        if (__fsqrt_rn(d2) < THRF) hit = true;
    }
    return hit;
}

// ---------- Main: gt mask + prune mask + losses ----------
__global__ __launch_bounds__(256) void main_k(const float* __restrict__ scores,
                                              const float* __restrict__ points,
                                              const float* __restrict__ ctrs,
                                              const uint32_t* __restrict__ ws,
                                              float* __restrict__ out) {
    const int b = blockIdx.y;
    const uint32_t* st = ws + STATE_OFF + b * 2;
    const float T = __uint_as_float(st[0]);
    const uint32_t Istar = st[1];

    const int p0 = blockIdx.x * 1024 + threadIdx.x * 4;
    if (p0 >= NPTS) return;

    const float* P = points + ((size_t)b * NPTS + p0) * 3;
    const float4 a = *reinterpret_cast<const float4*>(P);
    const float4 c4 = *reinterpret_cast<const float4*>(P + 4);
    const float4 e = *reinterpret_cast<const float4*>(P + 8);
    const float px[4] = {a.x, a.w, c4.z, e.y};
    const float py[4] = {a.y, c4.x, c4.w, e.z};
    const float pz[4] = {a.z, c4.y, e.x, e.w};
    // d^2 = p.p + (c.c - 2 p.c); min commutes with +p.p (per-point constant)
    float m2[4] = {1e30f, 1e30f, 1e30f, 1e30f};

    const float* C = ctrs + b * NBOX * 3;
#pragma unroll 16
    for (int k = 0; k < NBOX; ++k) {
        const float cx = C[3 * k + 0];
        const float cy = C[3 * k + 1];
        const float cz = C[3 * k + 2];
        const float cc = fmaf(cx, cx, fmaf(cy, cy, cz * cz));
        const float m2x = -2.0f * cx, m2y = -2.0f * cy, m2z = -2.0f * cz;
#pragma unroll
        for (int j = 0; j < 4; ++j) {
            const float t = fmaf(m2x, px[j], fmaf(m2y, py[j], fmaf(m2z, pz[j], cc)));
            m2[j] = fminf(m2[j], t);
        }
    }

    const float4 sv = *reinterpret_cast<const float4*>(scores + (size_t)b * NPTS + p0);
    const float s[4] = {sv.x, sv.y, sv.z, sv.w};
    float pr[4], ls[4];
#pragma unroll
    for (int j = 0; j < 4; ++j) {
        const float pp = fmaf(px[j], px[j], fmaf(py[j], py[j], pz[j] * pz[j]));
        const float m = pp + m2[j];
        bool gt;
        if (m < C_LO) gt = true;
        else if (m >= C_HI) gt = false;
        else gt = exact_gt(px[j], py[j], pz[j], C);  // rare boundary band
        const bool sm = (s[j] > T) || (s[j] == T && (uint32_t)(p0 + j) < Istar);
        pr[j] = (gt || sm) ? 1.0f : 0.0f;
        const float x = gt ? -s[j] : s[j];
        ls[j] = fmaxf(x, 0.0f) + log1pf(expf(-fabsf(x)));
    }
    float* o0 = out + (size_t)b * NPTS + p0;
    float* o1 = out + (size_t)BB * NPTS + (size_t)b * NPTS + p0;
    *reinterpret_cast<float4*>(o0) = make_float4(pr[0], pr[1], pr[2], pr[3]);
    *reinterpret_cast<float4*>(o1) = make_float4(ls[0], ls[1], ls[2], ls[3]);
}

extern "C" void kernel_launch(void* const* d_in, const int* in_sizes, int n_in,
                              void* d_out, int out_size, void* d_ws, size_t ws_size,
                              hipStream_t stream) {
    const float* scores = (const float*)d_in[0];
    const float* points = (const float*)d_in[1];
    const float* ctrs   = (const float*)d_in[2];
    float* out = (float*)d_out;
    uint32_t* ws = (uint32_t*)d_ws;

    const dim3 gridP(HSLICES, BB);  // 98 x 16
    bucket_k<<<gridP, 256, 0, stream>>>(scores, ws);
    select_k<<<BB, 1024, 0, stream>>>(scores, ws);
    main_k<<<gridP, 256, 0, stream>>>(scores, points, ctrs, ws, out);
}